// Round 4
// baseline (50.834 us; speedup 1.0000x reference)
//
#include <hip/hip_runtime.h>

#define NN 16
constexpr int BB = 32, CIN = 64, HH = 112, WW = 112;
constexpr int HWC = HH * WW;          // 12544
constexpr int COUT = 128, HW2 = 56 * 56;
constexpr int NE = 64;
constexpr int NQ = HWC / 4;           // 3136 float4 pixels per image
constexpr int QPB = 64;               // pixel-quads per conv block
constexpr int BPI = NQ / QPB;         // 49 conv blocks per image (exact)
constexpr int PF4 = COUT * HW2 / 4;   // 100352 float4 per batch
constexpr int SBPB = 25;              // scale blocks per batch

// ---------------- Kernel 1: 1x1 conv (channel-split) + segment scatter -----
// 256 threads = 64 pixel-quads x 4 channel-groups; LDS combine; scatter is
// fully parallel: 256 threads x 1 pixel x 4 atomics into 8-replica skewed acc.
__global__ __launch_bounds__(256) void k_conv_seg(
    const float* __restrict__ Bfor, const int* __restrict__ seg,
    const float* __restrict__ convw, float* __restrict__ part)
{
    __shared__ float w[CIN];
    __shared__ float ps[4][QPB * 5];    // [cg][quad*5+px], stride-5 bank skew
    __shared__ float acc[8 * 80];       // [replica][node*5+st], skewed banks
    const int tid = threadIdx.x;
    const int b   = blockIdx.x / BPI;
    const int blk = blockIdx.x % BPI;
    const int cg  = tid >> 6;           // channel group == wave id
    const int l   = tid & 63;           // quad lane

    if (tid < CIN) w[tid] = convw[tid];
    for (int i = tid; i < 8 * 80; i += 256) acc[i] = 0.f;
    __syncthreads();

    const int p = (blk * QPB + l) * 4;
    const float* base = Bfor + (size_t)b * CIN * HWC + (size_t)(cg * 16) * HWC + p;

    float4 s = make_float4(0.f, 0.f, 0.f, 0.f);
    #pragma unroll
    for (int cc = 0; cc < 16; ++cc) {
        const float4 v = *reinterpret_cast<const float4*>(base + (size_t)cc * HWC);
        const float wc = w[cg * 16 + cc];
        s.x = fmaf(v.x, wc, s.x);
        s.y = fmaf(v.y, wc, s.y);
        s.z = fmaf(v.z, wc, s.z);
        s.w = fmaf(v.w, wc, s.w);
    }
    ps[cg][l * 5 + 0] = s.x;
    ps[cg][l * 5 + 1] = s.y;
    ps[cg][l * 5 + 2] = s.z;
    ps[cg][l * 5 + 3] = s.w;
    __syncthreads();

    {   // parallel scatter: thread t -> pixel (quad t>>2, px t&3)
        const int q  = tid >> 2, px = tid & 3;
        const float v = ps[0][q * 5 + px] + ps[1][q * 5 + px]
                      + ps[2][q * 5 + px] + ps[3][q * 5 + px];
        const int pp  = blk * 256 + tid;            // == (blk*QPB+q)*4+px
        const int sgv = seg[(size_t)b * HWC + pp];  // coalesced
        const float row = (float)(pp / WW);
        const float col = (float)(pp % WW);
        const int k = tid & 7;                      // replica
        float* a = &acc[k * 80 + sgv * 5];
        atomicAdd(a + 0, row);
        atomicAdd(a + 1, col);
        atomicAdd(a + 2, v);
        atomicAdd(a + 3, 1.f);
    }
    __syncthreads();

    if (tid < NN * 4) {
        const int node = tid >> 2, st = tid & 3;
        float v = 0.f;
        #pragma unroll
        for (int k = 0; k < 8; ++k) v += acc[k * 80 + node * 5 + st];
        part[((b * BPI + blk) * NN + node) * 4 + st] = v;
    }
}

// ------- Kernel 2: fused graph stage (redundant per block) + broadcast scale
__global__ __launch_bounds__(256) void k_graph_scale(
    const float* __restrict__ part, const int* __restrict__ src,
    const int* __restrict__ dst,  const float* __restrict__ convb,
    const float* __restrict__ W1, const float* __restrict__ b1,
    const float* __restrict__ W2, const float* __restrict__ b2,
    const float* __restrict__ fcw, const float* __restrict__ fcb,
    const float* __restrict__ Bfon, float* __restrict__ out)
{
    const int b    = blockIdx.x / SBPB;
    const int blkb = blockIdx.x % SBPB;
    const int tid  = threadIdx.x;

    __shared__ float X[NN][4];
    __shared__ float A[NN][NN];
    __shared__ float nrm[NN];
    __shared__ float h1s[NN][32];
    __shared__ float agg[NN][32];
    __shared__ float pred[4][64];
    __shared__ float gpart[2][COUT];
    __shared__ float Gs[COUT];

    // ---- Phase A: tiny graph network (redundant across SBPB blocks) ----
    {   // reduce 49 conv-block partials: 4 chunks x <=13 loads, coalesced
        const int id = tid & 63, chunk = tid >> 6;
        float v = 0.f;
        const int k0 = chunk * 13, k1e = (k0 + 13 < BPI) ? k0 + 13 : BPI;
        for (int k = k0; k < k1e; ++k) v += part[(size_t)(b * BPI + k) * 64 + id];
        pred[chunk][id] = v;
    }
    for (int i = tid; i < NN * NN; i += 256) ((float*)A)[i] = 0.f;
    __syncthreads();

    if (tid < 64) {
        const int node = tid >> 2, st = tid & 3;
        X[node][st] = pred[0][tid] + pred[1][tid] + pred[2][tid] + pred[3][tid];
    }
    __syncthreads();

    if (tid < NN) {        // raw sums -> features (conv bias folded in)
        const float cnt = X[tid][3];
        const float cs  = fmaxf(cnt, 1.f);
        X[tid][0] = X[tid][0] / cs;
        X[tid][1] = X[tid][1] / cs;
        X[tid][2] = (X[tid][2] + cnt * convb[0]) / cs;
    }
    __syncthreads();

    // normalize feature cols 2,3 across nodes (mean, std ddof=1)
    if (tid < 2) {
        const int c = 2 + tid;
        float mu = 0.f;
        for (int i = 0; i < NN; ++i) mu += X[i][c];
        mu *= (1.f / NN);
        float var = 0.f;
        for (int i = 0; i < NN; ++i) { const float d = X[i][c] - mu; var = fmaf(d, d, var); }
        var *= (1.f / (NN - 1));
        const float inv = 1.f / (sqrtf(var) + 1.f);
        for (int i = 0; i < NN; ++i) X[i][c] = (X[i][c] - mu) * inv;
    }
    // build adjacency (idempotent set-to-1)
    if (tid >= 64 && tid < 64 + NE) {
        const int e = tid - 64;
        const int s = src[b * NE + e], d = dst[b * NE + e];
        A[s][d] = 1.f;
        A[d][s] = 1.f;
    }
    __syncthreads();

    if (tid < NN) {
        float rs = 0.f;
        for (int j = 0; j < NN; ++j) rs += A[tid][j];
        nrm[tid] = 1.f / sqrtf(fmaxf(rs, 1.f));
    }
    __syncthreads();

    if (tid < NN * 4) {    // agg1 (16x4)
        const int i = tid >> 2, k = tid & 3;
        float s = 0.f;
        for (int j = 0; j < NN; ++j) s = fmaf(A[i][j] * nrm[j], X[j][k], s);
        agg[i][k] = s;
    }
    __syncthreads();

    for (int t = tid; t < NN * 32; t += 256) {   // h1 (16x32)
        const int i = t >> 5, f = t & 31;
        float s = 0.f;
        #pragma unroll
        for (int k = 0; k < 4; ++k) s = fmaf(agg[i][k], W1[k * 32 + f], s);
        h1s[i][f] = fmaxf(fmaf(nrm[i], s, b1[f]), 0.f);
    }
    __syncthreads();

    for (int t = tid; t < NN * 32; t += 256) {   // agg2 (16x32)
        const int i = t >> 5, k = t & 31;
        float s = 0.f;
        for (int j = 0; j < NN; ++j) s = fmaf(A[i][j] * nrm[j], h1s[j][k], s);
        agg[i][k] = s;
    }
    __syncthreads();

    {   // h2 + FC, i-range split across 2 half-blocks
        const int f = tid & 127, half = tid >> 7;
        float g = 0.f;
        const float bf = b2[f];
        for (int i = half * 8; i < half * 8 + 8; ++i) {
            float s = 0.f;
            #pragma unroll
            for (int k = 0; k < 32; ++k) s = fmaf(agg[i][k], W2[k * COUT + f], s);
            g = fmaf(fcw[i], fmaxf(fmaf(nrm[i], s, bf), 0.f), g);
        }
        gpart[half][f] = g;
    }
    __syncthreads();
    if (tid < COUT) Gs[tid] = gpart[0][tid] + gpart[1][tid] + fcb[0];
    __syncthreads();

    // ---- Phase B: out[b,c,:,:] = Gs[c] * B_fon[b,c,:,:] (this block's slice)
    const float4* bf4 = reinterpret_cast<const float4*>(Bfon) + (size_t)b * PF4;
    float4*       ob4 = reinterpret_cast<float4*>(out)        + (size_t)b * PF4;
    for (int t = blkb * 256 + tid; t < PF4; t += SBPB * 256) {
        const float4 v = bf4[t];
        const float  g = Gs[t / (HW2 / 4)];   // 784 float4s per (b,c) plane
        ob4[t] = make_float4(v.x * g, v.y * g, v.z * g, v.w * g);
    }
}

extern "C" void kernel_launch(void* const* d_in, const int* in_sizes, int n_in,
                              void* d_out, int out_size, void* d_ws, size_t ws_size,
                              hipStream_t stream)
{
    const float* Bfor  = (const float*)d_in[0];
    const float* Bfon  = (const float*)d_in[1];
    const int*   seg   = (const int*)d_in[2];
    const int*   src   = (const int*)d_in[3];
    const int*   dst   = (const int*)d_in[4];
    const float* convw = (const float*)d_in[5];
    const float* convb = (const float*)d_in[6];
    const float* W1    = (const float*)d_in[7];
    const float* b1    = (const float*)d_in[8];
    const float* W2    = (const float*)d_in[9];
    const float* b2    = (const float*)d_in[10];
    const float* fcw   = (const float*)d_in[11];
    const float* fcb   = (const float*)d_in[12];

    float* part = (float*)d_ws;           // BB*BPI*NN*4 floats = 401 KB
    float* out  = (float*)d_out;

    k_conv_seg<<<BB * BPI, 256, 0, stream>>>(Bfor, seg, convw, part);
    k_graph_scale<<<BB * SBPB, 256, 0, stream>>>(part, src, dst, convb,
                                                 W1, b1, W2, b2, fcw, fcb,
                                                 Bfon, out);
}